// Round 7
// baseline (168.728 us; speedup 1.0000x reference)
//
#include <hip/hip_runtime.h>
#include <math.h>

#define T_SEQ 2048
#define NH    32
#define NKV   8
#define HS    128
#define FD    64
#define NBLK  32          // T_SEQ / 64
#define SCAN_NB 30        // k_main reads S_cum[B-2], B<=31 -> b<=29
#define EPSF  1e-12f
#define LDP   136         // LDS row pitch (bf16 elems)
#define STP   129         // ST pitch in rows (128 d rows + 1 z row)

typedef unsigned short u16;
typedef __bf16 bf16x8 __attribute__((ext_vector_type(8)));
typedef float  f32x4  __attribute__((ext_vector_type(4)));

__device__ __forceinline__ u16 f2b(float f) {
  unsigned u = __builtin_bit_cast(unsigned, f);
  return (u16)((u + 0x7fffu + ((u >> 16) & 1u)) >> 16);
}

// ws layout (bytes):
//  FKT: bf16 [NH][128 f][T j]             16,777,216
//  ST : bf16 [NH][NBLK][129 d][128 f]     33,816,576  (row128=z)
//  VT : bf16 [NKV][128 d][T key]           4,194,304
//  WT : bf16 [2][NH][64 f][128 d]          1,048,576
//  KBB: bf16 [NKV][NBLK][64 k][128 d]      4,194,304
#define FKT_OFF 0
#define ST_OFF  16777216
#define VT_OFF  54525952
#define WT_OFF  58720256
#define KB_OFF  59768832

// ---------------- K0: fused weight transpose + V transpose ----------------
__global__ __launch_bounds__(256) void k_pre(
    const float* __restrict__ wq, const float* __restrict__ wk,
    const float* __restrict__ vg,
    u16* __restrict__ WT, u16* __restrict__ VT)
{
  __shared__ float sB[128 * 68];
  const int bx = blockIdx.x, tid = threadIdx.x;

  if (bx < 64) {
    const int h = bx >> 1, isk = bx & 1;
    const float* src = (isk ? wk : wq) + (size_t)h * HS * FD;
    for (int idx = tid * 4; idx < 8192; idx += 1024) {
      int r = idx >> 6, c = idx & 63;
      *(float4*)(sB + r * 68 + c) = *(const float4*)(src + idx);
    }
    __syncthreads();
    u16* dst = WT + ((size_t)(isk * NH + h)) * 8192;
    for (int i = 0; i < 8; ++i) {
      int ch = tid + i * 256;
      int f = ch >> 5, d4 = (ch & 31) * 4;
      ushort4 u;
      u.x = f2b(sB[(d4 + 0) * 68 + f]);
      u.y = f2b(sB[(d4 + 1) * 68 + f]);
      u.z = f2b(sB[(d4 + 2) * 68 + f]);
      u.w = f2b(sB[(d4 + 3) * 68 + f]);
      *(ushort4*)(dst + f * 128 + d4) = u;
    }
  } else {
    const int idx2 = bx - 64;
    const int b = idx2 & 31, kvh = idx2 >> 5;
    float* sV = sB;                        // 64*129 floats
    for (int idx = tid * 4; idx < 8192; idx += 1024) {
      int r = idx >> 7, c = idx & 127;
      *(float4*)(sV + r * 129 + c) = *(const float4*)(vg + (size_t)(b * 64 + r) * (NKV * HS) + kvh * HS + c);
    }
    __syncthreads();
    const int lane = tid & 63, w = tid >> 6;
#pragma unroll
    for (int i = 0; i < 32; ++i) {
      int d = w * 32 + i;
      VT[((size_t)(kvh * 128 + d)) * T_SEQ + b * 64 + lane] = f2b(sV[lane * 129 + d]);
    }
  }
}

// ---------------- K1: K feature maps (MFMA) + K bf16 tile dump ----------------
__global__ __launch_bounds__(256) void k_fmap(
    const float* __restrict__ kg, const u16* __restrict__ WT,
    u16* __restrict__ FKT, u16* __restrict__ KBB)
{
  __shared__ __align__(16) u16 smem[2 * 64 * 136];
  u16* sX = smem;
  u16* sW = smem + 64 * 136;
  const int lt = blockIdx.x, h = blockIdx.y;
  const int tid = threadIdx.x, lane = tid & 63, w = tid >> 6;
  const int quad = lane >> 4, txn = lane & 15;

  const float* xbase = kg + (h >> 2) * HS;
  const int    xstr  = NKV * HS;
  for (int idx = tid * 4; idx < 8192; idx += 1024) {
    int r = idx >> 7, c = idx & 127;
    float4 v4 = *(const float4*)(xbase + (size_t)(lt * 64 + r) * xstr + c);
    ushort4 u; u.x = f2b(v4.x); u.y = f2b(v4.y); u.z = f2b(v4.z); u.w = f2b(v4.w);
    *(ushort4*)(sX + r * 136 + c) = u;
  }
  const u16* wt = WT + ((size_t)(NH + h)) * 8192;
  for (int i = 0; i < 4; ++i) {
    int ch = tid + i * 256;
    int row = ch >> 4, d8 = (ch & 15) * 8;
    *(uint4*)(sW + row * 136 + d8) = *(const uint4*)(wt + row * 128 + d8);
  }
  __syncthreads();

  if ((h & 3) == 0) {
    u16* ob = KBB + ((size_t)((h >> 2) * NBLK + lt)) * 8192;
    for (int i = 0; i < 4; ++i) {
      int ch = tid + i * 256;
      int row = ch >> 4, d8 = (ch & 15) * 8;
      *(uint4*)(ob + row * 128 + d8) = *(const uint4*)(sX + row * 136 + d8);
    }
  }

  const int arow = w * 16 + txn;
  const f32x4 vzero = {0.f, 0.f, 0.f, 0.f};
  f32x4 zt[4] = {vzero, vzero, vzero, vzero};
#pragma unroll
  for (int ks = 0; ks < 4; ++ks) {
    bf16x8 a = *(const bf16x8*)(sX + arow * 136 + ks * 32 + quad * 8);
#pragma unroll
    for (int nt = 0; nt < 4; ++nt) {
      bf16x8 bb = *(const bf16x8*)(sW + (nt * 16 + txn) * 136 + ks * 32 + quad * 8);
      zt[nt] = __builtin_amdgcn_mfma_f32_16x16x32_bf16(a, bb, zt[nt], 0, 0, 0);
    }
  }

  float E1[4][4], E2[4][4];
#pragma unroll
  for (int r = 0; r < 4; ++r) {
    float zv[4];
    float mx = -1e30f, mn = 1e30f;
#pragma unroll
    for (int nt = 0; nt < 4; ++nt) {
      zv[nt] = zt[nt][r];
      mx = fmaxf(mx, zv[nt]); mn = fminf(mn, zv[nt]);
    }
#pragma unroll
    for (int o = 1; o < 16; o <<= 1) {
      mx = fmaxf(mx, __shfl_xor(mx, o));
      mn = fminf(mn, __shfl_xor(mn, o));
    }
    float e1[4], e2[4], s1 = 0.f, s2 = 0.f;
#pragma unroll
    for (int nt = 0; nt < 4; ++nt) {
      e1[nt] = __expf(zv[nt] - mx); s1 += e1[nt];
      e2[nt] = __expf(mn - zv[nt]); s2 += e2[nt];
    }
#pragma unroll
    for (int o = 1; o < 16; o <<= 1) { s1 += __shfl_xor(s1, o); s2 += __shfl_xor(s2, o); }
    float r1 = 1.f / s1, r2 = 1.f / s2;
#pragma unroll
    for (int nt = 0; nt < 4; ++nt) {
      E1[r][nt] = fmaxf(e1[nt] * r1, EPSF);
      E2[r][nt] = fmaxf(e2[nt] * r2, EPSF);
    }
  }

  __syncthreads();

#pragma unroll
  for (int r = 0; r < 4; ++r) {
    int j = w * 16 + quad * 4 + r;
#pragma unroll
    for (int nt = 0; nt < 4; ++nt) {
      sX[(nt * 16 + txn) * 68 + j]        = f2b(E1[r][nt]);
      sX[(nt * 16 + txn + 64) * 68 + j]   = f2b(E2[r][nt]);
    }
  }
  __syncthreads();
  u16* ob = FKT + (size_t)h * 128 * T_SEQ + lt * 64;
  for (int i = 0; i < 8; ++i) {
    int ch = tid + i * 256;
    int row = ch >> 4, j4 = (ch & 15) * 4;
    *(ushort4*)(ob + (size_t)row * T_SEQ + j4) = *(const ushort4*)(sX + row * 68 + j4);
  }
}

// ---------------- K2: fused state + prefix scan (double-buffered, 1 barrier/iter) ----------------
__global__ __launch_bounds__(256) void k_scan(
    const u16* __restrict__ FKT, const u16* __restrict__ VT, u16* __restrict__ ST)
{
  __shared__ __align__(16) u16 sVT[2][16 * 72];
  __shared__ __align__(16) u16 sFK[2][64 * 72];
  const int L = blockIdx.x + 8 * blockIdx.y + 16 * blockIdx.z;   // [0,512)
  const int xcd = L & 7, j = L >> 3;
  const int hsub = j & 3, fh = (j >> 2) & 1, dc = j >> 3;
  const int h = xcd * 4 + hsub;
  const int tid = threadIdx.x, lane = tid & 63, w = tid >> 6;
  const int quad = lane >> 4, txn = lane & 15;
  const bool doz = (dc == 0);

  bf16x8 vone;
#pragma unroll
  for (int jj = 0; jj < 8; ++jj) vone[jj] = (__bf16)1.0f;

  const u16* vbase = VT + ((size_t)((h >> 2) * 128 + dc * 16)) * T_SEQ;
  const u16* fbase = FKT + ((size_t)(h * 128 + fh * 64)) * T_SEQ;

  const int srow = tid >> 4, sj4 = (tid & 15) * 4;
  ushort4 rv, rf[4];
  rv = *(const ushort4*)(vbase + (size_t)srow * T_SEQ + sj4);
#pragma unroll
  for (int i = 0; i < 4; ++i) {
    int ch = tid + i * 256;
    int fr = ch >> 4, fj4 = (ch & 15) * 4;
    rf[i] = *(const ushort4*)(fbase + (size_t)fr * T_SEQ + fj4);
  }

  const f32x4 vzero = {0.f, 0.f, 0.f, 0.f};
  f32x4 acc = vzero, zacc = vzero;
  int cur = 0;

  for (int b = 0; b < SCAN_NB; ++b) {
    u16* dV = sVT[cur];
    u16* dF = sFK[cur];
    *(ushort4*)(dV + srow * 72 + sj4) = rv;
#pragma unroll
    for (int i = 0; i < 4; ++i) {
      int ch = tid + i * 256;
      int fr = ch >> 4, fj4 = (ch & 15) * 4;
      *(ushort4*)(dF + fr * 72 + fj4) = rf[i];
    }
    __syncthreads();            // dbuf: single barrier per iter
    if (b + 1 < SCAN_NB) {
      rv = *(const ushort4*)(vbase + (size_t)srow * T_SEQ + (b + 1) * 64 + sj4);
#pragma unroll
      for (int i = 0; i < 4; ++i) {
        int ch = tid + i * 256;
        int fr = ch >> 4, fj4 = (ch & 15) * 4;
        rf[i] = *(const ushort4*)(fbase + (size_t)fr * T_SEQ + (b + 1) * 64 + fj4);
      }
    }
#pragma unroll
    for (int ks = 0; ks < 2; ++ks) {
      bf16x8 a  = *(const bf16x8*)(dV + txn * 72 + ks * 32 + quad * 8);
      bf16x8 bb = *(const bf16x8*)(dF + (w * 16 + txn) * 72 + ks * 32 + quad * 8);
      acc = __builtin_amdgcn_mfma_f32_16x16x32_bf16(a, bb, acc, 0, 0, 0);
      if (doz) zacc = __builtin_amdgcn_mfma_f32_16x16x32_bf16(vone, bb, zacc, 0, 0, 0);
    }
    u16* Sb = ST + (((size_t)(h * NBLK + b)) * STP + dc * 16) * 128 + fh * 64;
#pragma unroll
    for (int r = 0; r < 4; ++r)
      Sb[(quad * 4 + r) * 128 + w * 16 + txn] = f2b(acc[r]);
    if (doz && quad == 0)
      ST[(((size_t)(h * NBLK + b)) * STP + 128) * 128 + fh * 64 + w * 16 + txn] = f2b(zacc[0]);
    cur ^= 1;
  }
}

// ---------------- K4: main attention — 8 waves, wave-pair split, double-buffered RB ----------------
// 1024 blocks x 512 thr; wave w: wq_=w&3 owns q-rows [wq_*16,+16), wt=w>>2 owns a t-half.
// RB0/RB1 alternate so every stage overlaps the other buffer's compute. 8 barriers total.
__global__ __launch_bounds__(512, 6) void k_main(
    const float* __restrict__ qg, const u16* __restrict__ KBB,
    const u16* __restrict__ WT, const u16* __restrict__ ST,
    const u16* __restrict__ VT, const float* __restrict__ wfac,
    float* __restrict__ out)
{
  __shared__ __align__(16) u16 RA[64 * LDP];    // Q -> P -> FQ (17408 B)
  __shared__ __align__(16) u16 RB0[64 * LDP];   // W -> qk1 -> v1 -> s1
  __shared__ __align__(16) u16 RB1[64 * LDP];   // qk0 -> v0 -> s0
  __shared__ __align__(16) u16 sz[128];         // z row of S_cum (256 B)
  __shared__ float sred[128];                   // m/ss exchange, slot-reused (512 B)
  const int L = blockIdx.x + 32 * blockIdx.y;
  const int xcd = L & 7, jj = L >> 3;
  const int hsub = jj & 3, B = jj >> 2;
  const int h = xcd * 4 + hsub;
  const int tid = threadIdx.x;
  const int lane = tid & 63, w = tid >> 6;      // w in [0,8)
  const int wq_ = w & 3, wt = w >> 2;
  const int quad = lane >> 4, txn = lane & 15;
  const int arow = wq_ * 16 + txn;
  const int koff = quad * 8;

  const f32x4 vzero = {0.f, 0.f, 0.f, 0.f};
  f32x4 y[4];
#pragma unroll
  for (int t = 0; t < 4; ++t) y[t] = vzero;
  float sln[4] = {0.f, 0.f, 0.f, 0.f};
  const bf16x8 bzero = {0, 0, 0, 0, 0, 0, 0, 0};

  const int kb0 = (B >= 1) ? B - 1 : 0;
  const u16* ktB = KBB + ((size_t)((h >> 2) * NBLK + B)) * 8192;
  const u16* ktP = KBB + ((size_t)((h >> 2) * NBLK + kb0)) * 8192;
  const u16* vts = VT  + (size_t)((h >> 2) * 128) * T_SEQ;
  const u16* wqt = WT  + (size_t)h * 8192;
  const u16* ssrc = ST + ((size_t)(h * NBLK + (B >= 2 ? B - 2 : 0))) * (STP * 128);

  // staging helpers (512 threads; full 64x128 tile = 2 uint4/thread)
  auto stage_full = [&](u16* dst, const u16* __restrict__ src) {
#pragma unroll
    for (int i = 0; i < 2; ++i) {
      int idx = tid * 8 + i * 4096, rr = idx >> 7, c = idx & 127;
      *(uint4*)(dst + rr * LDP + c) = *(const uint4*)(src + idx);
    }
  };
  auto stage_qk = [&](u16* dst, int p) {        // rows 0..31 = K[B] keys p*32.., 32..63 = K[B-1]
#pragma unroll
    for (int i = 0; i < 2; ++i) {
      int idx = tid * 8 + i * 4096, rr = idx >> 7, c = idx & 127;
      const u16* src = (rr < 32) ? (ktB + (p * 32 + rr) * 128)
                                 : (ktP + (p * 32 + rr - 32) * 128);
      *(uint4*)(dst + rr * LDP + c) = *(const uint4*)(src + c);
    }
  };
  auto stage_v = [&](u16* dst, int p) {         // rows 0..31 = d p*32.., 32..63 = d 64+p*32..
#pragma unroll
    for (int i = 0; i < 2; ++i) {
      int idx = tid * 8 + i * 4096, rr = idx >> 7, c = idx & 127;
      int d = (rr < 32) ? (p * 32 + rr) : (64 + p * 32 + rr - 32);
      int key = (c < 64) ? (kb0 * 64 + c) : (B * 64 + (c - 64));
      *(uint4*)(dst + rr * LDP + c) = *(const uint4*)(vts + (size_t)d * T_SEQ + key);
    }
  };
  auto stage_s = [&](u16* dst, int p) {
#pragma unroll
    for (int i = 0; i < 2; ++i) {
      int idx = tid * 8 + i * 4096, rr = idx >> 7, c = idx & 127;
      int d = (rr < 32) ? (p * 32 + rr) : (64 + p * 32 + rr - 32);
      *(uint4*)(dst + rr * LDP + c) = *(const uint4*)(ssrc + d * 128 + c);
    }
  };

  // ---- seg A: stage Q -> RA, W -> RB0, qk-pair0 -> RB1 ----
#pragma unroll
  for (int i = 0; i < 4; ++i) {
    int idx = tid * 4 + i * 2048;
    int r = idx >> 7, c = idx & 127;
    float4 v4 = *(const float4*)(qg + (size_t)(B * 64 + r) * (NH * HS) + h * HS + c);
    ushort4 u; u.x = f2b(v4.x); u.y = f2b(v4.y); u.z = f2b(v4.z); u.w = f2b(v4.w);
    *(ushort4*)(RA + r * LDP + c) = u;
  }
  if (B >= 2) stage_full(RB0, wqt);
  stage_qk(RB1, 0);
  __syncthreads();                              // bar1

  // ---- seg B: z = Q·W (RB0) + QK^T p0 (RB1) ----
  f32x4 zt[4] = {vzero, vzero, vzero, vzero};
  if (B >= 2) {
#pragma unroll
    for (int ks = 0; ks < 4; ++ks) {
      bf16x8 a = *(const bf16x8*)(RA + arow * LDP + ks * 32 + koff);
#pragma unroll
      for (int nt = 0; nt < 4; ++nt) {
        bf16x8 bb = *(const bf16x8*)(RB0 + (nt * 16 + txn) * LDP + ks * 32 + koff);
        zt[nt] = __builtin_amdgcn_mfma_f32_16x16x32_bf16(a, bb, zt[nt], 0, 0, 0);
      }
    }
  }
  f32x4 s[4];
#pragma unroll
  for (int t = 0; t < 4; ++t) s[t] = vzero;
#pragma unroll
  for (int ks = 0; ks < 4; ++ks) {
    bf16x8 a = *(const bf16x8*)(RA + arow * LDP + ks * 32 + koff);
#pragma unroll
    for (int tl = 0; tl < 2; ++tl) {
      if (wt == 0 && B == 0) continue;
      int row = (wt ? 0 : 32) + tl * 16 + txn;
      bf16x8 bb = *(const bf16x8*)(RB1 + row * LDP + ks * 32 + koff);
      s[tl] = __builtin_amdgcn_mfma_f32_16x16x32_bf16(a, bb, s[tl], 0, 0, 0);
    }
  }
  __syncthreads();                              // bar2

  // ---- seg C: stage qk-pair1 -> RB0, v-pair0 -> RB1; fmap softmax VALU ----
  stage_qk(RB0, 1);
  stage_v(RB1, 0);
  unsigned Epk[4][4];
  if (B >= 2) {
#pragma unroll
    for (int r = 0; r < 4; ++r) {
      float zv[4];
      float mx = -1e30f, mn = 1e30f;
#pragma unroll
      for (int nt = 0; nt < 4; ++nt) {
        zv[nt] = zt[nt][r];
        mx = fmaxf(mx, zv[nt]); mn = fminf(mn, zv[nt]);
      }
#pragma unroll
      for (int o = 1; o < 16; o <<= 1) {
        mx = fmaxf(mx, __shfl_xor(mx, o));
        mn = fminf(mn, __shfl_xor(mn, o));
      }
      float e1[4], e2[4], s1 = 0.f, s2 = 0.f;
#pragma unroll
      for (int nt = 0; nt < 4; ++nt) {
        e1[nt] = __expf(zv[nt] - mx); s1 += e1[nt];
        e2[nt] = __expf(mn - zv[nt]); s2 += e2[nt];
      }
#pragma unroll
      for (int o = 1; o < 16; o <<= 1) { s1 += __shfl_xor(s1, o); s2 += __shfl_xor(s2, o); }
      float r1 = 1.f / s1, r2 = 1.f / s2;
#pragma unroll
      for (int nt = 0; nt < 4; ++nt) {
        unsigned lo = f2b(fmaxf(e1[nt] * r1, EPSF));
        unsigned hi = f2b(fmaxf(e2[nt] * r2, EPSF));
        Epk[r][nt] = lo | (hi << 16);
      }
    }
  }
  __syncthreads();                              // bar3

  // ---- seg D: QK^T p1 (RB0); softmax step 1 (masks, per-half max -> sred) ----
#pragma unroll
  for (int ks = 0; ks < 4; ++ks) {
    bf16x8 a = *(const bf16x8*)(RA + arow * LDP + ks * 32 + koff);
#pragma unroll
    for (int tl = 0; tl < 2; ++tl) {
      if (wt == 0 && B == 0) continue;
      int row = (wt ? 0 : 32) + tl * 16 + txn;
      bf16x8 bb = *(const bf16x8*)(RB0 + row * LDP + ks * 32 + koff);
      s[2 + tl] = __builtin_amdgcn_mfma_f32_16x16x32_bf16(a, bb, s[2 + tl], 0, 0, 0);
    }
  }
  float wf = wfac[h];
  wf = 1.f / (1.f + __expf(-wf));
  const float scale = 0.08838834764831845f;
  float mh[4];
#pragma unroll
  for (int r = 0; r < 4; ++r) {
    const int irow = wq_ * 16 + quad * 4 + r;
    float m = -1e30f;
#pragma unroll
    for (int sl = 0; sl < 4; ++sl) {
      float x = s[sl][r] * scale;
      bool msk = wt ? (sl * 16 + txn > irow) : (B == 0);
      x = msk ? -1e30f : x;
      s[sl][r] = x;
      m = fmaxf(m, x);
    }
#pragma unroll
    for (int o = 1; o < 16; o <<= 1) m = fmaxf(m, __shfl_xor(m, o));
    mh[r] = m;
  }
  if (txn == 0) {
#pragma unroll
    for (int r = 0; r < 4; ++r) sred[wt * 64 + wq_ * 16 + quad * 4 + r] = mh[r];
  }
  __syncthreads();                              // bar4

  // ---- seg E: softmax finish (read partner m, write P, ss -> partner's m slot); stage v1 -> RB0 ----
  stage_v(RB0, 1);                              // qk1 reads done at bar4
  float ssum[4];
#pragma unroll
  for (int r = 0; r < 4; ++r) {
    const int irow = wq_ * 16 + quad * 4 + r;
    float m = fmaxf(mh[r], sred[(wt ^ 1) * 64 + wq_ * 16 + quad * 4 + r]);
    float ss = 0.f;
#pragma unroll
    for (int sl = 0; sl < 4; ++sl) {
      float e = (s[sl][r] > -1e29f) ? wf * __expf(s[sl][r] - m) : 0.f;
      ss += e;
      RA[irow * LDP + wt * 64 + sl * 16 + txn] = f2b(e);
    }
#pragma unroll
    for (int o = 1; o < 16; o <<= 1) ss += __shfl_xor(ss, o);
    ssum[r] = ss;
  }
  if (txn == 0) {                               // reuse partner's m slot (only I read it)
#pragma unroll
    for (int r = 0; r < 4; ++r) sred[(wt ^ 1) * 64 + wq_ * 16 + quad * 4 + r] = ssum[r];
  }
  __syncthreads();                              // bar5

  // ---- seg F: combine ssum; PV p0 (RB1 v0) ----
#pragma unroll
  for (int r = 0; r < 4; ++r)
    ssum[r] += sred[wt * 64 + wq_ * 16 + quad * 4 + r];
#pragma unroll
  for (int ks = 0; ks < 4; ++ks) {
    if (B == 0 && ks < 2) continue;
    bf16x8 a = *(const bf16x8*)(RA + arow * LDP + ks * 32 + koff);
#pragma unroll
    for (int tl = 0; tl < 2; ++tl) {
      int row = wt * 32 + tl * 16 + txn;
      bf16x8 bb = *(const bf16x8*)(RB1 + row * LDP + ks * 32 + koff);
      y[tl] = __builtin_amdgcn_mfma_f32_16x16x32_bf16(a, bb, y[tl], 0, 0, 0);
    }
  }
  __syncthreads();                              // bar6

  // ---- seg G: stage s0 -> RB1, sz; PV p1 (RB0 v1) ----
  stage_s(RB1, 0);
  if (tid < 32) *(ushort4*)(sz + tid * 4) = *(const ushort4*)(ssrc + 16384 + tid * 4);
#pragma unroll
  for (int ks = 0; ks < 4; ++ks) {
    if (B == 0 && ks < 2) continue;
    bf16x8 a = *(const bf16x8*)(RA + arow * LDP + ks * 32 + koff);
#pragma unroll
    for (int tl = 0; tl < 2; ++tl) {
      int row = wt * 32 + tl * 16 + txn;
      bf16x8 bb = *(const bf16x8*)(RB0 + row * LDP + ks * 32 + koff);
      y[2 + tl] = __builtin_amdgcn_mfma_f32_16x16x32_bf16(a, bb, y[2 + tl], 0, 0, 0);
    }
  }
  __syncthreads();                              // bar7: all PV reads of P done

  // ---- seg H: FQ unpack -> RA (own stripe, own half); stage s1 -> RB0 ----
  if (B >= 2) {
#pragma unroll
    for (int r = 0; r < 4; ++r) {
      int row = wq_ * 16 + quad * 4 + r;
#pragma unroll
      for (int nt = 0; nt < 4; ++nt) {
        u16 val = wt ? (u16)(Epk[r][nt] >> 16) : (u16)(Epk[r][nt] & 0xffffu);
        RA[row * LDP + wt * 64 + nt * 16 + txn] = val;
      }
    }
  }
  stage_s(RB0, 1);                              // v1 reads done at bar7
  __syncthreads();                              // bar8

  // ---- seg I: linear p0 (RB1 s0) + yz; linear p1 (RB0 s1); epilogue ----
  f32x4 yz = vzero;
  if (B >= 2) {
#pragma unroll
    for (int ks = 0; ks < 4; ++ks) {
      bf16x8 a = *(const bf16x8*)(RA + arow * LDP + ks * 32 + koff);
#pragma unroll
      for (int tl = 0; tl < 2; ++tl) {
        int row = wt * 32 + tl * 16 + txn;
        bf16x8 bb = *(const bf16x8*)(RB1 + row * LDP + ks * 32 + koff);
        y[tl] = __builtin_amdgcn_mfma_f32_16x16x32_bf16(a, bb, y[tl], 0, 0, 0);
      }
      bf16x8 bz = (txn == 0) ? *(const bf16x8*)(sz + ks * 32 + koff) : bzero;
      yz = __builtin_amdgcn_mfma_f32_16x16x32_bf16(a, bz, yz, 0, 0, 0);
    }
#pragma unroll
    for (int ks = 0; ks < 4; ++ks) {
      bf16x8 a = *(const bf16x8*)(RA + arow * LDP + ks * 32 + koff);
#pragma unroll
      for (int tl = 0; tl < 2; ++tl) {
        int row = wt * 32 + tl * 16 + txn;
        bf16x8 bb = *(const bf16x8*)(RB0 + row * LDP + ks * 32 + koff);
        y[2 + tl] = __builtin_amdgcn_mfma_f32_16x16x32_bf16(a, bb, y[2 + tl], 0, 0, 0);
      }
    }
#pragma unroll
    for (int r = 0; r < 4; ++r) sln[r] = __shfl(yz[r], lane & 48);
  }

  const size_t obase = ((size_t)h * T_SEQ + B * 64) * HS;
#pragma unroll
  for (int r = 0; r < 4; ++r) {
    float inv = 1.f / (ssum[r] + sln[r]);
    int irow = wq_ * 16 + quad * 4 + r;
#pragma unroll
    for (int yl = 0; yl < 4; ++yl) {
      int t = wt * 4 + yl;
      out[obase + (size_t)irow * HS + t * 16 + txn] = y[yl][r] * inv;
    }
  }
}

extern "C" void kernel_launch(void* const* d_in, const int* in_sizes, int n_in,
                              void* d_out, int out_size, void* d_ws, size_t ws_size,
                              hipStream_t stream) {
  const float* q    = (const float*)d_in[0];
  const float* k    = (const float*)d_in[1];
  const float* v    = (const float*)d_in[2];
  const float* wq   = (const float*)d_in[3];
  const float* wk   = (const float*)d_in[4];
  const float* wfac = (const float*)d_in[5];
  float* out = (float*)d_out;
  char* wsb = (char*)d_ws;

  u16* FKT = (u16*)(wsb + FKT_OFF);
  u16* ST  = (u16*)(wsb + ST_OFF);
  u16* VT  = (u16*)(wsb + VT_OFF);
  u16* WT  = (u16*)(wsb + WT_OFF);
  u16* KBB = (u16*)(wsb + KB_OFF);

  k_pre  <<<dim3(320),      256, 0, stream>>>(wq, wk, v, WT, VT);
  k_fmap <<<dim3(NBLK, NH), 256, 0, stream>>>(k, WT, FKT, KBB);
  k_scan <<<dim3(8, 2, NH), 256, 0, stream>>>(FKT, VT, ST);
  k_main <<<dim3(NBLK, NH), 512, 0, stream>>>(q, KBB, WT, ST, VT, wfac, out);
}

// Round 8
// 160.277 us; speedup vs baseline: 1.0527x; 1.0527x over previous
//
#include <hip/hip_runtime.h>
#include <math.h>

#define T_SEQ 2048
#define NH    32
#define NKV   8
#define HS    128
#define FD    64
#define NBLK  32          // T_SEQ / 64
#define SCAN_NB 30        // k_main reads S_cum[B-2], B<=31 -> b<=29
#define EPSF  1e-12f
#define LDP   136         // LDS row pitch (bf16 elems)
#define STP   129         // ST pitch in rows (128 d rows + 1 z row)

typedef unsigned short u16;
typedef __bf16 bf16x8 __attribute__((ext_vector_type(8)));
typedef float  f32x4  __attribute__((ext_vector_type(4)));

__device__ __forceinline__ u16 f2b(float f) {
  unsigned u = __builtin_bit_cast(unsigned, f);
  return (u16)((u + 0x7fffu + ((u >> 16) & 1u)) >> 16);
}

// ws layout (bytes):
//  FKT: bf16 [NH][32 lt][128 f][64 j]     16,777,216   (tile-contiguous)
//  ST : bf16 [NH][NBLK][129 d][128 f]     33,816,576   (row128=z)
//  VT : bf16 [NKV][128 d][T key]           4,194,304
//  WT : bf16 [NH][64 f][128 d]               524,288   (q-side only)
//  KBB: bf16 [NKV][NBLK][64 k][128 d]      4,194,304
#define FKT_OFF 0
#define ST_OFF  16777216
#define VT_OFF  54525952
#define WT_OFF  58720256
#define KB_OFF  59768832

// ---- in-phase staging: contiguous bf16 64x128 tile -> LDS (pitch LDP), 256 thr ----
__device__ __forceinline__ void stage_bf(u16* buf, const u16* __restrict__ src, int tid) {
#pragma unroll
  for (int i = 0; i < 4; ++i) {
    int idx = tid * 8 + i * 2048, rr = idx >> 7, c = idx & 127;
    *(uint4*)(buf + rr * LDP + c) = *(const uint4*)(src + idx);
  }
}
// V^T rows (stride T_SEQ), key window remap -> LDS
__device__ __forceinline__ void stage_vt(u16* buf, const u16* __restrict__ vts,
                                         int rofs, int kb0, int B, int tid) {
#pragma unroll
  for (int i = 0; i < 4; ++i) {
    int idx = tid * 8 + i * 2048, rr = idx >> 7, c = idx & 127;
    int key = (c < 64) ? (kb0 * 64 + c) : (B * 64 + (c - 64));
    *(uint4*)(buf + rr * LDP + c) = *(const uint4*)(vts + (size_t)(rr + rofs) * T_SEQ + key);
  }
}

// ---------------- K1: merged prep ----------------
// 1312 blocks: [0,32) WTq transpose, [32,288) V transpose, [288,1312) K feature maps
__global__ __launch_bounds__(256) void k_prep(
    const float* __restrict__ wq, const float* __restrict__ wk,
    const float* __restrict__ vg, const float* __restrict__ kg,
    u16* __restrict__ WT, u16* __restrict__ VT,
    u16* __restrict__ FKT, u16* __restrict__ KBB)
{
  __shared__ __align__(16) u16 smem[2 * 64 * 136];   // 34816 B
  const int bx = blockIdx.x, tid = threadIdx.x;
  const int lane = tid & 63, w = tid >> 6;
  const int quad = lane >> 4, txn = lane & 15;

  if (bx < 32) {
    // ---- WTq transpose: h = bx ----
    float* sB = (float*)smem;                  // 128*68 f32 = 34816 B
    const float* src = wq + (size_t)bx * HS * FD;
    for (int idx = tid * 4; idx < 8192; idx += 1024) {
      int r = idx >> 6, c = idx & 63;
      *(float4*)(sB + r * 68 + c) = *(const float4*)(src + idx);
    }
    __syncthreads();
    u16* dst = WT + (size_t)bx * 8192;
    for (int i = 0; i < 8; ++i) {
      int ch = tid + i * 256;
      int f = ch >> 5, d4 = (ch & 31) * 4;
      ushort4 u;
      u.x = f2b(sB[(d4 + 0) * 68 + f]);
      u.y = f2b(sB[(d4 + 1) * 68 + f]);
      u.z = f2b(sB[(d4 + 2) * 68 + f]);
      u.w = f2b(sB[(d4 + 3) * 68 + f]);
      *(ushort4*)(dst + f * 128 + d4) = u;
    }
    return;
  }

  if (bx < 288) {
    // ---- V transpose: idx2 = bx-32 -> (b, kvh) ----
    const int idx2 = bx - 32;
    const int b = idx2 & 31, kvh = idx2 >> 5;
    float* sV = (float*)smem;                  // 64*129 f32 = 33024 B
    for (int idx = tid * 4; idx < 8192; idx += 1024) {
      int r = idx >> 7, c = idx & 127;
      *(float4*)(sV + r * 129 + c) = *(const float4*)(vg + (size_t)(b * 64 + r) * (NKV * HS) + kvh * HS + c);
    }
    __syncthreads();
#pragma unroll
    for (int i = 0; i < 32; ++i) {
      int d = w * 32 + i;
      VT[((size_t)(kvh * 128 + d)) * T_SEQ + b * 64 + lane] = f2b(sV[lane * 129 + d]);
    }
    return;
  }

  // ---- K feature map: j2 = bx-288 -> (lt, h) ----
  const int j2 = bx - 288;
  const int lt = j2 & 31, h = j2 >> 5;
  u16* sX = smem;              // X tile [k][d] pitch 136
  u16* sW = smem + 64 * 136;   // W^T rows [f][d] pitch 136

  // K tile f32 -> bf16 -> LDS
  const float* xbase = kg + (h >> 2) * HS;
  const int    xstr  = NKV * HS;
  for (int idx = tid * 4; idx < 8192; idx += 1024) {
    int r = idx >> 7, c = idx & 127;
    float4 v4 = *(const float4*)(xbase + (size_t)(lt * 64 + r) * xstr + c);
    ushort4 u; u.x = f2b(v4.x); u.y = f2b(v4.y); u.z = f2b(v4.z); u.w = f2b(v4.w);
    *(ushort4*)(sX + r * 136 + c) = u;
  }
  // W_k self-transpose: wk[h] is [128 d][64 f] f32; sW[f][d] bf16
  {
    const float* wsrc = wk + (size_t)h * (HS * FD);
    const int d = tid >> 1, f0 = (tid & 1) * 32;
#pragma unroll
    for (int i = 0; i < 8; ++i) {
      float4 v4 = *(const float4*)(wsrc + d * 64 + f0 + i * 4);
      sW[(f0 + i * 4 + 0) * 136 + d] = f2b(v4.x);
      sW[(f0 + i * 4 + 1) * 136 + d] = f2b(v4.y);
      sW[(f0 + i * 4 + 2) * 136 + d] = f2b(v4.z);
      sW[(f0 + i * 4 + 3) * 136 + d] = f2b(v4.w);
    }
  }
  __syncthreads();

  // dump bf16 K tile for k_main (once per kvh)
  if ((h & 3) == 0) {
    u16* ob = KBB + ((size_t)((h >> 2) * NBLK + lt)) * 8192;
    for (int i = 0; i < 4; ++i) {
      int ch = tid + i * 256;
      int row = ch >> 4, d8 = (ch & 15) * 8;
      *(uint4*)(ob + row * 128 + d8) = *(const uint4*)(sX + row * 136 + d8);
    }
  }

  const int arow = w * 16 + txn;
  const f32x4 vzero = {0.f, 0.f, 0.f, 0.f};
  f32x4 zt[4] = {vzero, vzero, vzero, vzero};
#pragma unroll
  for (int ks = 0; ks < 4; ++ks) {
    bf16x8 a = *(const bf16x8*)(sX + arow * 136 + ks * 32 + quad * 8);
#pragma unroll
    for (int nt = 0; nt < 4; ++nt) {
      bf16x8 bb = *(const bf16x8*)(sW + (nt * 16 + txn) * 136 + ks * 32 + quad * 8);
      zt[nt] = __builtin_amdgcn_mfma_f32_16x16x32_bf16(a, bb, zt[nt], 0, 0, 0);
    }
  }

  float E1[4][4], E2[4][4];
#pragma unroll
  for (int r = 0; r < 4; ++r) {
    float zv[4];
    float mx = -1e30f, mn = 1e30f;
#pragma unroll
    for (int nt = 0; nt < 4; ++nt) {
      zv[nt] = zt[nt][r];
      mx = fmaxf(mx, zv[nt]); mn = fminf(mn, zv[nt]);
    }
#pragma unroll
    for (int o = 1; o < 16; o <<= 1) {
      mx = fmaxf(mx, __shfl_xor(mx, o));
      mn = fminf(mn, __shfl_xor(mn, o));
    }
    float e1[4], e2[4], s1 = 0.f, s2 = 0.f;
#pragma unroll
    for (int nt = 0; nt < 4; ++nt) {
      e1[nt] = __expf(zv[nt] - mx); s1 += e1[nt];
      e2[nt] = __expf(mn - zv[nt]); s2 += e2[nt];
    }
#pragma unroll
    for (int o = 1; o < 16; o <<= 1) { s1 += __shfl_xor(s1, o); s2 += __shfl_xor(s2, o); }
    float r1 = 1.f / s1, r2 = 1.f / s2;
#pragma unroll
    for (int nt = 0; nt < 4; ++nt) {
      E1[r][nt] = fmaxf(e1[nt] * r1, EPSF);
      E2[r][nt] = fmaxf(e2[nt] * r2, EPSF);
    }
  }

  __syncthreads();

  // transpose into sX [128 f][64 j] pitch 68
#pragma unroll
  for (int r = 0; r < 4; ++r) {
    int j = w * 16 + quad * 4 + r;
#pragma unroll
    for (int nt = 0; nt < 4; ++nt) {
      sX[(nt * 16 + txn) * 68 + j]        = f2b(E1[r][nt]);
      sX[(nt * 16 + txn + 64) * 68 + j]   = f2b(E2[r][nt]);
    }
  }
  __syncthreads();
  // tiled FKT write: contiguous 16 KB per block
  u16* ob = FKT + ((size_t)(h * 32 + lt)) * 8192;
  for (int i = 0; i < 8; ++i) {
    int ch = tid + i * 256;
    int row = ch >> 4, j4 = (ch & 15) * 4;
    *(ushort4*)(ob + row * 64 + j4) = *(const ushort4*)(sX + row * 68 + j4);
  }
}

// ---------------- K2: fused state + prefix scan (dbuf, 1 barrier/iter, tiled FKT) ----------------
__global__ __launch_bounds__(256) void k_scan(
    const u16* __restrict__ FKT, const u16* __restrict__ VT, u16* __restrict__ ST)
{
  __shared__ __align__(16) u16 sVT[2][16 * 72];
  __shared__ __align__(16) u16 sFK[2][64 * 72];
  const int L = blockIdx.x + 8 * blockIdx.y + 16 * blockIdx.z;   // [0,512)
  const int xcd = L & 7, j = L >> 3;
  const int hsub = j & 3, fh = (j >> 2) & 1, dc = j >> 3;
  const int h = xcd * 4 + hsub;
  const int tid = threadIdx.x, lane = tid & 63, w = tid >> 6;
  const int quad = lane >> 4, txn = lane & 15;
  const bool doz = (dc == 0);

  bf16x8 vone;
#pragma unroll
  for (int jj = 0; jj < 8; ++jj) vone[jj] = (__bf16)1.0f;

  const u16* vbase = VT + ((size_t)((h >> 2) * 128 + dc * 16)) * T_SEQ;
  const u16* fbase = FKT + (size_t)(h * 32) * 8192 + fh * 4096;  // + b*8192 per iter

  const int srow = tid >> 4, sj4 = (tid & 15) * 4;
  ushort4 rv, rf[4];
  rv = *(const ushort4*)(vbase + (size_t)srow * T_SEQ + sj4);
#pragma unroll
  for (int i = 0; i < 4; ++i) {
    int ch = tid + i * 256;
    int fr = ch >> 4, fj4 = (ch & 15) * 4;
    rf[i] = *(const ushort4*)(fbase + fr * 64 + fj4);
  }

  const f32x4 vzero = {0.f, 0.f, 0.f, 0.f};
  f32x4 acc = vzero, zacc = vzero;
  int cur = 0;

  for (int b = 0; b < SCAN_NB; ++b) {
    u16* dV = sVT[cur];
    u16* dF = sFK[cur];
    *(ushort4*)(dV + srow * 72 + sj4) = rv;
#pragma unroll
    for (int i = 0; i < 4; ++i) {
      int ch = tid + i * 256;
      int fr = ch >> 4, fj4 = (ch & 15) * 4;
      *(ushort4*)(dF + fr * 72 + fj4) = rf[i];
    }
    __syncthreads();            // dbuf: single barrier per iter
    if (b + 1 < SCAN_NB) {
      rv = *(const ushort4*)(vbase + (size_t)srow * T_SEQ + (b + 1) * 64 + sj4);
#pragma unroll
      for (int i = 0; i < 4; ++i) {
        int ch = tid + i * 256;
        int fr = ch >> 4, fj4 = (ch & 15) * 4;
        rf[i] = *(const ushort4*)(fbase + (size_t)(b + 1) * 8192 + fr * 64 + fj4);
      }
    }
#pragma unroll
    for (int ks = 0; ks < 2; ++ks) {
      bf16x8 a  = *(const bf16x8*)(dV + txn * 72 + ks * 32 + quad * 8);
      bf16x8 bb = *(const bf16x8*)(dF + (w * 16 + txn) * 72 + ks * 32 + quad * 8);
      acc = __builtin_amdgcn_mfma_f32_16x16x32_bf16(a, bb, acc, 0, 0, 0);
      if (doz) zacc = __builtin_amdgcn_mfma_f32_16x16x32_bf16(vone, bb, zacc, 0, 0, 0);
    }
    u16* Sb = ST + (((size_t)(h * NBLK + b)) * STP + dc * 16) * 128 + fh * 64;
#pragma unroll
    for (int r = 0; r < 4; ++r)
      Sb[(quad * 4 + r) * 128 + w * 16 + txn] = f2b(acc[r]);
    if (doz && quad == 0)
      ST[(((size_t)(h * NBLK + b)) * STP + 128) * 128 + fh * 64 + w * 16 + txn] = f2b(zacc[0]);
    cur ^= 1;
  }
}

// ---------------- K4: main attention (R2 structure, W-direct z, 11 barriers) ----------------
// 1024 blocks, 256 threads = 4 waves; wave w owns q-rows [w*16, w*16+16)
__global__ __launch_bounds__(256, 4) void k_main(
    const float* __restrict__ qg, const u16* __restrict__ KBB,
    const u16* __restrict__ WT, const u16* __restrict__ ST,
    const u16* __restrict__ VT, const float* __restrict__ wfac,
    float* __restrict__ out)
{
  __shared__ __align__(16) u16 RA[64 * LDP];   // A-operand: Q -> P -> FQ (wave-private stripes)
  __shared__ __align__(16) u16 RB[64 * LDP];   // B-operand: K[B] -> K[B-1] -> V^T -> S
  __shared__ __align__(16) u16 sz[128];        // z row of S_cum
  const int L = blockIdx.x + 32 * blockIdx.y;  // [0,1024)
  const int xcd = L & 7, jj = L >> 3;
  const int hsub = jj & 3, B = jj >> 2;
  const int h = xcd * 4 + hsub;
  const int tid = threadIdx.x;
  const int lane = tid & 63, w = tid >> 6;
  const int quad = lane >> 4, txn = lane & 15;
  const int arow = w * 16 + txn;
  const int koff = quad * 8;

  const f32x4 vzero = {0.f, 0.f, 0.f, 0.f};
  f32x4 y[8];
#pragma unroll
  for (int t = 0; t < 8; ++t) y[t] = vzero;
  float sln[4] = {0.f, 0.f, 0.f, 0.f};
  const bf16x8 bzero = {0, 0, 0, 0, 0, 0, 0, 0};

  const int kb0 = (B >= 1) ? B - 1 : 0;
  const u16* ktB = KBB + ((size_t)((h >> 2) * NBLK + B)) * 8192;
  const u16* ktP = KBB + ((size_t)((h >> 2) * NBLK + kb0)) * 8192;
  const u16* vts = VT  + (size_t)((h >> 2) * 128) * T_SEQ;
  const u16* wqt = WT  + (size_t)h * 8192;
  const u16* ssrc = ST + ((size_t)(h * NBLK + (B >= 2 ? B - 2 : 0))) * (STP * 128);

  // ---- wave-private Q stage (no barrier) ----
  {
    const float* qb = qg + (size_t)(B * 64 + w * 16) * (NH * HS) + h * HS;
#pragma unroll
    for (int i = 0; i < 8; ++i) {
      int idx = lane + i * 64;               // 0..511
      int r = idx >> 5, c4 = (idx & 31) * 4;
      float4 v4 = *(const float4*)(qb + (size_t)r * (NH * HS) + c4);
      ushort4 u; u.x = f2b(v4.x); u.y = f2b(v4.y); u.z = f2b(v4.z); u.w = f2b(v4.w);
      *(ushort4*)(RA + (w * 16 + r) * LDP + c4) = u;
    }
  }
  stage_bf(RB, ktB, tid);                    // K[B] -> RB (no readers until W1)

  // ---- z = Q·W (W direct from global; proven in R4) ----
  f32x4 zt[4] = {vzero, vzero, vzero, vzero};
  if (B >= 2) {
#pragma unroll
    for (int ks = 0; ks < 4; ++ks) {
      bf16x8 a = *(const bf16x8*)(RA + arow * LDP + ks * 32 + koff);
#pragma unroll
      for (int nt = 0; nt < 4; ++nt) {
        bf16x8 bb = *(const bf16x8*)(wqt + (nt * 16 + txn) * 128 + ks * 32 + koff);
        zt[nt] = __builtin_amdgcn_mfma_f32_16x16x32_bf16(a, bb, zt[nt], 0, 0, 0);
      }
    }
  }

  // ---- feature-map softmax -> packed bf16 (E1 lo | E2 hi) ----
  unsigned Epk[4][4];
  if (B >= 2) {
#pragma unroll
    for (int r = 0; r < 4; ++r) {
      float zv[4];
      float mx = -1e30f, mn = 1e30f;
#pragma unroll
      for (int nt = 0; nt < 4; ++nt) {
        zv[nt] = zt[nt][r];
        mx = fmaxf(mx, zv[nt]); mn = fminf(mn, zv[nt]);
      }
#pragma unroll
      for (int o = 1; o < 16; o <<= 1) {
        mx = fmaxf(mx, __shfl_xor(mx, o));
        mn = fminf(mn, __shfl_xor(mn, o));
      }
      float e1[4], e2[4], s1 = 0.f, s2 = 0.f;
#pragma unroll
      for (int nt = 0; nt < 4; ++nt) {
        e1[nt] = __expf(zv[nt] - mx); s1 += e1[nt];
        e2[nt] = __expf(mn - zv[nt]); s2 += e2[nt];
      }
#pragma unroll
      for (int o = 1; o < 16; o <<= 1) { s1 += __shfl_xor(s1, o); s2 += __shfl_xor(s2, o); }
      float r1 = 1.f / s1, r2 = 1.f / s2;
#pragma unroll
      for (int nt = 0; nt < 4; ++nt) {
        unsigned lo = f2b(fmaxf(e1[nt] * r1, EPSF));
        unsigned hi = f2b(fmaxf(e2[nt] * r2, EPSF));
        Epk[r][nt] = lo | (hi << 16);
      }
    }
  }
  __syncthreads();                           // W1: K[B] staged

  // ---- QK^T diagonal block -> s[4..7] ----
  f32x4 s[8];
#pragma unroll
  for (int t = 0; t < 8; ++t) s[t] = vzero;
#pragma unroll
  for (int ks = 0; ks < 4; ++ks) {
    bf16x8 a = *(const bf16x8*)(RA + arow * LDP + ks * 32 + koff);
#pragma unroll
    for (int t = 0; t < 4; ++t) {
      bf16x8 bb = *(const bf16x8*)(RB + (t * 16 + txn) * LDP + ks * 32 + koff);
      s[4 + t] = __builtin_amdgcn_mfma_f32_16x16x32_bf16(a, bb, s[4 + t], 0, 0, 0);
    }
  }

  if (B >= 1) {
    __syncthreads();                         // R1
    stage_bf(RB, ktP, tid);                  // K[B-1]
    __syncthreads();                         // W2
#pragma unroll
    for (int ks = 0; ks < 4; ++ks) {
      bf16x8 a = *(const bf16x8*)(RA + arow * LDP + ks * 32 + koff);
#pragma unroll
      for (int t = 0; t < 4; ++t) {
        bf16x8 bb = *(const bf16x8*)(RB + (t * 16 + txn) * LDP + ks * 32 + koff);
        s[t] = __builtin_amdgcn_mfma_f32_16x16x32_bf16(a, bb, s[t], 0, 0, 0);
      }
    }
  }

  // ---- masked softmax, write P (bf16) into own RA stripe ----
  float wf = wfac[h];
  wf = 1.f / (1.f + __expf(-wf));
  const float scale = 0.08838834764831845f;
  float ssum[4];
#pragma unroll
  for (int r = 0; r < 4; ++r) {
    const int irow = w * 16 + quad * 4 + r;
    float sv[8];
    float m = -1e30f;
#pragma unroll
    for (int t = 0; t < 8; ++t) {
      float x = s[t][r] * scale;
      bool msk = (t < 4) ? (B == 0) : ((t - 4) * 16 + txn > irow);
      x = msk ? -1e30f : x;
      sv[t] = x;
      m = fmaxf(m, x);
    }
#pragma unroll
    for (int o = 1; o < 16; o <<= 1) m = fmaxf(m, __shfl_xor(m, o));
    float ss = 0.f;
#pragma unroll
    for (int t = 0; t < 8; ++t) {
      float e = (sv[t] > -1e29f) ? wf * __expf(sv[t] - m) : 0.f;
      ss += e;
      RA[irow * LDP + t * 16 + txn] = f2b(e);
    }
#pragma unroll
    for (int o = 1; o < 16; o <<= 1) ss += __shfl_xor(ss, o);
    ssum[r] = ss;
  }
  __syncthreads();                           // R2: all waves done reading RB (K)

  // ---- V^T lo -> PV t=0..3 ----
  stage_vt(RB, vts, 0, kb0, B, tid);
  __syncthreads();                           // W3
#pragma unroll
  for (int ks = 0; ks < 4; ++ks) {
    if (B == 0 && ks < 2) continue;
    bf16x8 a = *(const bf16x8*)(RA + arow * LDP + ks * 32 + koff);
#pragma unroll
    for (int t = 0; t < 4; ++t) {
      bf16x8 bb = *(const bf16x8*)(RB + (t * 16 + txn) * LDP + ks * 32 + koff);
      y[t] = __builtin_amdgcn_mfma_f32_16x16x32_bf16(a, bb, y[t], 0, 0, 0);
    }
  }
  __syncthreads();                           // R3

  // ---- V^T hi -> PV t=4..7 ----
  stage_vt(RB, vts, 64, kb0, B, tid);
  __syncthreads();                           // W4
#pragma unroll
  for (int ks = 0; ks < 4; ++ks) {
    if (B == 0 && ks < 2) continue;
    bf16x8 a = *(const bf16x8*)(RA + arow * LDP + ks * 32 + koff);
#pragma unroll
    for (int t = 4; t < 8; ++t) {
      bf16x8 bb = *(const bf16x8*)(RB + (t * 16 + txn - 64) * LDP + ks * 32 + koff);
      y[t] = __builtin_amdgcn_mfma_f32_16x16x32_bf16(a, bb, y[t], 0, 0, 0);
    }
  }

  // ---- linear part: Y += FQ · S_cum[B-2]  (+ z -> sln) ----
  if (B >= 2) {
    __syncthreads();                         // R4: V^T hi reads done
#pragma unroll
    for (int r = 0; r < 4; ++r) {            // FQ unpack into own stripe (P dead)
      int row = w * 16 + quad * 4 + r;
#pragma unroll
      for (int nt = 0; nt < 4; ++nt) {
        RA[row * LDP + nt * 16 + txn]      = (u16)(Epk[r][nt] & 0xffffu);
        RA[row * LDP + 64 + nt * 16 + txn] = (u16)(Epk[r][nt] >> 16);
      }
    }
    stage_bf(RB, ssrc, tid);                 // S^T d-rows 0..63
    if (tid < 32) *(ushort4*)(sz + tid * 4) = *(const ushort4*)(ssrc + 16384 + tid * 4);
    __syncthreads();                         // W5
    f32x4 yz = vzero;
#pragma unroll
    for (int ks = 0; ks < 4; ++ks) {
      bf16x8 a = *(const bf16x8*)(RA + arow * LDP + ks * 32 + koff);
#pragma unroll
      for (int t = 0; t < 4; ++t) {
        bf16x8 bb = *(const bf16x8*)(RB + (t * 16 + txn) * LDP + ks * 32 + koff);
        y[t] = __builtin_amdgcn_mfma_f32_16x16x32_bf16(a, bb, y[t], 0, 0, 0);
      }
      bf16x8 bz = (txn == 0) ? *(const bf16x8*)(sz + ks * 32 + koff) : bzero;
      yz = __builtin_amdgcn_mfma_f32_16x16x32_bf16(a, bz, yz, 0, 0, 0);
    }
    __syncthreads();                         // R5
    stage_bf(RB, ssrc + 8192, tid);          // S^T d-rows 64..127
    __syncthreads();                         // W6
#pragma unroll
    for (int ks = 0; ks < 4; ++ks) {
      bf16x8 a = *(const bf16x8*)(RA + arow * LDP + ks * 32 + koff);
#pragma unroll
      for (int t = 4; t < 8; ++t) {
        bf16x8 bb = *(const bf16x8*)(RB + (t * 16 + txn - 64) * LDP + ks * 32 + koff);
        y[t] = __builtin_amdgcn_mfma_f32_16x16x32_bf16(a, bb, y[t], 0, 0, 0);
      }
    }
#pragma unroll
    for (int r = 0; r < 4; ++r) sln[r] = __shfl(yz[r], lane & 48);
  }

  // ---- epilogue ----
  const size_t obase = ((size_t)h * T_SEQ + B * 64) * HS;
#pragma unroll
  for (int r = 0; r < 4; ++r) {
    float inv = 1.f / (ssum[r] + sln[r]);
    int irow = w * 16 + quad * 4 + r;
#pragma unroll
    for (int t = 0; t < 8; ++t)
      out[obase + (size_t)irow * HS + t * 16 + txn] = y[t][r] * inv;
  }
}

extern "C" void kernel_launch(void* const* d_in, const int* in_sizes, int n_in,
                              void* d_out, int out_size, void* d_ws, size_t ws_size,
                              hipStream_t stream) {
  const float* q    = (const float*)d_in[0];
  const float* k    = (const float*)d_in[1];
  const float* v    = (const float*)d_in[2];
  const float* wq   = (const float*)d_in[3];
  const float* wk   = (const float*)d_in[4];
  const float* wfac = (const float*)d_in[5];
  float* out = (float*)d_out;
  char* wsb = (char*)d_ws;

  u16* FKT = (u16*)(wsb + FKT_OFF);
  u16* ST  = (u16*)(wsb + ST_OFF);
  u16* VT  = (u16*)(wsb + VT_OFF);
  u16* WT  = (u16*)(wsb + WT_OFF);
  u16* KBB = (u16*)(wsb + KB_OFF);

  k_prep <<<dim3(1312),     256, 0, stream>>>(wq, wk, v, k, WT, VT, FKT, KBB);
  k_scan <<<dim3(8, 2, NH), 256, 0, stream>>>(FKT, VT, ST);
  k_main <<<dim3(NBLK, NH), 256, 0, stream>>>(q, KBB, WT, ST, VT, wfac, out);
}